// Round 8
// baseline (463.350 us; speedup 1.0000x reference)
//
#include <hip/hip_runtime.h>

typedef unsigned short u16;
typedef unsigned int u32;
typedef __attribute__((ext_vector_type(8))) __bf16 bf16x8;
typedef __attribute__((ext_vector_type(8))) unsigned short u16x8;
typedef __attribute__((ext_vector_type(4))) float f32x4;
typedef __attribute__((ext_vector_type(16))) float f32x16;
typedef __attribute__((ext_vector_type(4))) unsigned int u32x4;
typedef __attribute__((ext_vector_type(4))) unsigned short u16x4;

#define MFMA16(a, b, c) __builtin_amdgcn_mfma_f32_16x16x32_bf16(a, b, c, 0, 0, 0)
#define MFMA32(a, b, c) __builtin_amdgcn_mfma_f32_32x32x16_bf16(a, b, c, 0, 0, 0)

#if __has_builtin(__builtin_amdgcn_exp2f)
#define EXP2(x) __builtin_amdgcn_exp2f(x)
#else
#define EXP2(x) exp2f(x)
#endif

__device__ __forceinline__ u16 f2b(float f) {
  u32 u = __builtin_bit_cast(u32, f);
  u = (u + 0x7fffu + ((u >> 16) & 1u)) >> 16;
  return (u16)u;
}

__device__ __forceinline__ u32 pkbf(float lo, float hi) {
  __bf16 a = (__bf16)lo, b = (__bf16)hi;
  return (u32)__builtin_bit_cast(u16, a) | ((u32)__builtin_bit_cast(u16, b) << 16);
}

__device__ __forceinline__ void gload16(const void* g, void* s) {
  __builtin_amdgcn_global_load_lds((const __attribute__((address_space(1))) void*)g,
                                   (__attribute__((address_space(3))) void*)s, 16, 0, 0);
}

// ---------------- cast x (fp32 -> bf16), 8 elems/thread ----------------
__global__ __launch_bounds__(256) void cast_x_k(const float* __restrict__ x,
                                                u16* __restrict__ xb) {
  int i = blockIdx.x * 256 + threadIdx.x;
  const float4* xv = (const float4*)x;
  float4 a = xv[2 * i], b = xv[2 * i + 1];
  u16x8 o;
  o[0] = f2b(a.x); o[1] = f2b(a.y); o[2] = f2b(a.z); o[3] = f2b(a.w);
  o[4] = f2b(b.x); o[5] = f2b(b.y); o[6] = f2b(b.z); o[7] = f2b(b.w);
  ((u16x8*)xb)[i] = o;
}

// ---------------- transpose + cast weights: W[k][n] fp32 -> Wt[n][k] bf16 ----------------
__global__ __launch_bounds__(256) void transpose_w_k(
    const float* __restrict__ W0, const float* __restrict__ W1,
    const float* __restrict__ W2, const float* __restrict__ W3,
    u16* __restrict__ T0, u16* __restrict__ T1, u16* __restrict__ T2, u16* __restrict__ T3) {
  int z = blockIdx.z;
  const float* W = (z == 0) ? W0 : (z == 1) ? W1 : (z == 2) ? W2 : W3;
  u16* T = (z == 0) ? T0 : (z == 1) ? T1 : (z == 2) ? T2 : T3;
  __shared__ float tile[32][33];
  int n0 = blockIdx.x * 32, k0 = blockIdx.y * 32;
  int tx = threadIdx.x, ty = threadIdx.y;  // block (32,8)
#pragma unroll
  for (int r = 0; r < 32; r += 8)
    tile[ty + r][tx] = W[(size_t)(k0 + ty + r) * 1024 + n0 + tx];
  __syncthreads();
#pragma unroll
  for (int r = 0; r < 32; r += 8)
    T[(size_t)(n0 + ty + r) * 1024 + k0 + tx] = f2b(tile[tx][ty + r]);
}

// ---------------- 128x128 bf16 MFMA GEMM, K=N=1024 ----------------
// mode 0: out = head-major bf16 [(b*16+h)][s][hd]
// mode 1: out = fp32 [M][1024]
// mode 2: out = V-transposed bf16 [(b*16+h)][hd][s]
__global__ __launch_bounds__(256) void gemm128_k(
    const u16* __restrict__ A, const u16* __restrict__ Bt, const float* __restrict__ bias,
    u16* __restrict__ outb, float* __restrict__ outf, int mode) {
  __shared__ u16 Asm[128 * 32];
  __shared__ u16 Bsm[128 * 32];
  const int K = 1024;
  int bm = blockIdx.x, bn = blockIdx.y;
  int tid = threadIdx.x;
  int lane = tid & 63, wave = tid >> 6;
  int wm = wave >> 1, wn = wave & 1;
  int r = lane & 15, kg = (lane >> 4) * 8;
  f32x4 acc[4][4] = {};
  const u16* Abase = A + (size_t)bm * 128 * K;
  const u16* Bbase = Bt + (size_t)bn * 128 * K;
  for (int k0 = 0; k0 < K; k0 += 32) {
#pragma unroll
    for (int i = 0; i < 2; i++) {
      int c = tid + i * 256;
      int row = c >> 2, ko = (c & 3) * 8;
      gload16(Abase + (size_t)row * K + k0 + ko, Asm + c * 8);
      gload16(Bbase + (size_t)row * K + k0 + ko, Bsm + c * 8);
    }
    __syncthreads();
    bf16x8 af[4], bfr[4];
#pragma unroll
    for (int m = 0; m < 4; m++)
      af[m] = *(const bf16x8*)(Asm + (wm * 64 + m * 16 + r) * 32 + kg);
#pragma unroll
    for (int n = 0; n < 4; n++)
      bfr[n] = *(const bf16x8*)(Bsm + (wn * 64 + n * 16 + r) * 32 + kg);
#pragma unroll
    for (int m = 0; m < 4; m++)
#pragma unroll
      for (int n = 0; n < 4; n++)
        acc[m][n] = MFMA16(af[m], bfr[n], acc[m][n]);
    __syncthreads();
  }
#pragma unroll
  for (int m = 0; m < 4; m++) {
    int grow0 = bm * 128 + wm * 64 + m * 16 + ((lane >> 4) << 2);
#pragma unroll
    for (int n = 0; n < 4; n++) {
      int gcol = bn * 128 + wn * 64 + n * 16 + r;
      float bv = bias[gcol];
#pragma unroll
      for (int e = 0; e < 4; e++) {
        int grow = grow0 + e;
        float v = acc[m][n][e] + bv;
        if (mode == 0) {
          int b = grow >> 11, s = grow & 2047, h = gcol >> 6, hd = gcol & 63;
          outb[(((size_t)(b * 16 + h)) * 2048 + s) * 64 + hd] = f2b(v);
        } else if (mode == 2) {
          int b = grow >> 11, s = grow & 2047, h = gcol >> 6, hd = gcol & 63;
          outb[(((size_t)(b * 16 + h)) * 64 + hd) * 2048 + s] = f2b(v);
        } else {
          outf[(size_t)grow * 1024 + gcol] = v;
        }
      }
    }
  }
}

// ---------------- flash attention: LDS-free, swapped-operand, 1-tile software pipeline ----
// Q,K: [bh][s][64] bf16. VT: [bh][hd=64][s=2048] bf16. O: [b][s][1024] bf16.
// Block = 256 thr (4 waves), each wave owns 32 q-rows.
// Grid (bh=64, qt=16): id%8 = bh%8 -> per-XCD K/V working set = 4MB = L2 (verified r6).
// Pipeline: iteration kt issues QK^T(kt+1) MFMAs FIRST (consumed next iter -> full
// tile of latency cover), then softmax/pack/PV of tile kt. Tree reductions cut the
// serial fmax/sum chains from depth 31 to depth 5.
__global__ __launch_bounds__(256, 2) void attn_k(const u16* __restrict__ Q,
                                                 const u16* __restrict__ Kh,
                                                 const u16* __restrict__ VT,
                                                 u16* __restrict__ O) {
  int bh = blockIdx.x, qt = blockIdx.y;
  int tid = threadIdx.x, lane = tid & 63, w = tid >> 6;
  int c = lane & 31, h = lane >> 5;
  const size_t hoff = (size_t)bh * 2048 * 64;
  const u16* Qb = Q + hoff;
  const u16* Kb = Kh + hoff;
  const u16* Vb = VT + hoff;  // [64][2048]
  const int q = qt * 128 + w * 32 + c;
  const float cs = 0.125f * 1.44269504f;  // softmax scale in log2 domain

  // Q as B-fragments: lane(c,h) holds Q[q=c][d = ks*16 + 8h + j]
  bf16x8 qf[4];
#pragma unroll
  for (int ks = 0; ks < 4; ks++)
    qf[ks] = *(const bf16x8*)(Qb + (size_t)q * 64 + ks * 16 + h * 8);

  f32x16 oacc[2] = {};  // O^T frags: oacc[no]: hd = no*32 + (e&3)+8*(e>>2)+4h, col q = c
  float m_run = -1e30f, l_run = 0.f;

  // prologue: st = QK^T(tile 0); kf <- K(1)
  bf16x8 kf[2][4];
#pragma unroll
  for (int n = 0; n < 2; n++)
#pragma unroll
    for (int ks = 0; ks < 4; ks++)
      kf[n][ks] = *(const bf16x8*)(Kb + (size_t)(n * 32 + c) * 64 + ks * 16 + h * 8);
  f32x16 st[2] = {};
#pragma unroll
  for (int n = 0; n < 2; n++)
#pragma unroll
    for (int ks = 0; ks < 4; ks++)
      st[n] = MFMA32(kf[n][ks], qf[ks], st[n]);
#pragma unroll
  for (int n = 0; n < 2; n++)
#pragma unroll
    for (int ks = 0; ks < 4; ks++)
      kf[n][ks] = *(const bf16x8*)(Kb + 4096 + (size_t)(n * 32 + c) * 64 + ks * 16 + h * 8);

  for (int kt = 0; kt < 32; kt++) {
    // V(kt): issued first, consumed at PV (~full softmax of cover)
    bf16x8 vf[2][4];
#pragma unroll
    for (int no = 0; no < 2; no++)
#pragma unroll
      for (int sl = 0; sl < 4; sl++)
        vf[no][sl] =
            *(const bf16x8*)(Vb + (size_t)(no * 32 + c) * 2048 + kt * 64 + sl * 16 + h * 8);
    // QK^T(kt+1): MFMAs issued now, results needed only next iteration
    f32x16 stn[2] = {};
#pragma unroll
    for (int n = 0; n < 2; n++)
#pragma unroll
      for (int ks = 0; ks < 4; ks++)
        stn[n] = MFMA32(kf[n][ks], qf[ks], stn[n]);
    // K(kt+2): reload kf (consumed next iteration's stn)
    {
      int ktn = kt + 2 < 32 ? kt + 2 : 31;
      const u16* Ktn = Kb + (size_t)ktn * 4096;
#pragma unroll
      for (int n = 0; n < 2; n++)
#pragma unroll
        for (int ks = 0; ks < 4; ks++)
          kf[n][ks] = *(const bf16x8*)(Ktn + (size_t)(n * 32 + c) * 64 + ks * 16 + h * 8);
    }
    // ---- softmax of tile kt (tree reductions, depth 5) ----
    float tr[16];
#pragma unroll
    for (int e = 0; e < 16; e++) tr[e] = fmaxf(st[0][e], st[1][e]);
#pragma unroll
    for (int s = 8; s > 0; s >>= 1)
#pragma unroll
      for (int e = 0; e < 8; e++)
        if (e < s) tr[e] = fmaxf(tr[e], tr[e + s]);
    float pmax = fmaxf(tr[0], __shfl_xor(tr[0], 32));
    float ps = pmax * cs;
    // defer-max (T13): rescale only when max grew past THR=8 (log2 domain)
    if (__any(ps > m_run + 8.0f)) {
      float mnew = fmaxf(m_run, ps);
      float corr = EXP2(m_run - mnew);
      m_run = mnew;
      l_run *= corr;
#pragma unroll
      for (int no = 0; no < 2; no++)
#pragma unroll
        for (int e = 0; e < 16; e++) oacc[no][e] *= corr;
    }
#pragma unroll
    for (int n = 0; n < 2; n++)
#pragma unroll
      for (int e = 0; e < 16; e++) st[n][e] = EXP2(st[n][e] * cs - m_run);
#pragma unroll
    for (int e = 0; e < 16; e++) tr[e] = st[0][e] + st[1][e];
#pragma unroll
    for (int s = 8; s > 0; s >>= 1)
#pragma unroll
      for (int e = 0; e < 8; e++)
        if (e < s) tr[e] += tr[e + s];
    l_run += tr[0] + __shfl_xor(tr[0], 32);
    // ---- pack P to bf16 B-fragments via half-wave exchange ----
    u32 paw[4][4];
#pragma unroll
    for (int n = 0; n < 2; n++)
#pragma unroll
      for (int t = 0; t < 2; t++) {
        u32 A = pkbf(st[n][8 * t + 0], st[n][8 * t + 1]);
        u32 B = pkbf(st[n][8 * t + 2], st[n][8 * t + 3]);
        u32 C = pkbf(st[n][8 * t + 4], st[n][8 * t + 5]);
        u32 D = pkbf(st[n][8 * t + 6], st[n][8 * t + 7]);
        u32 t0 = __shfl_xor(h ? A : C, 32);
        u32 t1 = __shfl_xor(h ? B : D, 32);
        int sl = n * 2 + t;
        paw[sl][0] = h ? t0 : A;
        paw[sl][1] = h ? t1 : B;
        paw[sl][2] = h ? C : t0;
        paw[sl][3] = h ? D : t1;
      }
    // ---- PV: O^T += V^T . P^T ----
#pragma unroll
    for (int no = 0; no < 2; no++)
#pragma unroll
      for (int sl = 0; sl < 4; sl++) {
        bf16x8 pf = __builtin_bit_cast(bf16x8, *(u32x4*)paw[sl]);
        oacc[no] = MFMA32(vf[no][sl], pf, oacc[no]);
      }
    // rotate pipeline
    st[0] = stn[0];
    st[1] = stn[1];
  }
  // ---- epilogue: O^T[hd][q] / l -> O[b][s=q][head*64+hd] ----
  int b = bh >> 4, head = bh & 15;
  float inv = 1.0f / l_run;
#pragma unroll
  for (int no = 0; no < 2; no++)
#pragma unroll
    for (int u = 0; u < 4; u++) {
      u16x4 pkt;
#pragma unroll
      for (int v = 0; v < 4; v++) pkt[v] = f2b(oacc[no][4 * u + v] * inv);
      int hd0 = no * 32 + 8 * u + 4 * h;
      *(u16x4*)(O + ((size_t)b * 2048 + q) * 1024 + head * 64 + hd0) = pkt;
    }
}

extern "C" void kernel_launch(void* const* d_in, const int* in_sizes, int n_in,
                              void* d_out, int out_size, void* d_ws, size_t ws_size,
                              hipStream_t stream) {
  const float* x = (const float*)d_in[0];
  const float* Wq = (const float*)d_in[1];
  const float* bq = (const float*)d_in[2];
  const float* Wk = (const float*)d_in[3];
  const float* bk = (const float*)d_in[4];
  const float* Wv = (const float*)d_in[5];
  const float* bv = (const float*)d_in[6];
  const float* Wo = (const float*)d_in[7];
  const float* bo = (const float*)d_in[8];
  float* out = (float*)d_out;

  u16* ws = (u16*)d_ws;
  u16* x_bf = ws;                              // 8M u16
  u16* Wt0 = x_bf + 8 * 1024 * 1024;           // 1M each
  u16* Wt1 = Wt0 + 1024 * 1024;
  u16* Wt2 = Wt1 + 1024 * 1024;
  u16* Wt3 = Wt2 + 1024 * 1024;
  u16* Qh = Wt3 + 1024 * 1024;                 // 8M each
  u16* Kh = Qh + 8 * 1024 * 1024;
  u16* Vt = Kh + 8 * 1024 * 1024;              // V transposed [bh][hd][s]
  u16* attn = x_bf;  // alias: x_bf dead after QKV GEMMs

  cast_x_k<<<4096, 256, 0, stream>>>(x, x_bf);
  transpose_w_k<<<dim3(32, 32, 4), dim3(32, 8), 0, stream>>>(Wq, Wk, Wv, Wo, Wt0, Wt1, Wt2, Wt3);
  gemm128_k<<<dim3(64, 8), 256, 0, stream>>>(x_bf, Wt0, bq, Qh, nullptr, 0);
  gemm128_k<<<dim3(64, 8), 256, 0, stream>>>(x_bf, Wt1, bk, Kh, nullptr, 0);
  gemm128_k<<<dim3(64, 8), 256, 0, stream>>>(x_bf, Wt2, bv, Vt, nullptr, 2);
  attn_k<<<dim3(64, 16), 256, 0, stream>>>(Qh, Kh, Vt, attn);
  gemm128_k<<<dim3(64, 8), 256, 0, stream>>>(attn, Wt3, bo, nullptr, out, 1);
}

// Round 15
// 329.842 us; speedup vs baseline: 1.4048x; 1.4048x over previous
//
#include <hip/hip_runtime.h>

typedef unsigned short u16;
typedef unsigned int u32;
typedef __attribute__((ext_vector_type(8))) __bf16 bf16x8;
typedef __attribute__((ext_vector_type(8))) unsigned short u16x8;
typedef __attribute__((ext_vector_type(4))) float f32x4;
typedef __attribute__((ext_vector_type(16))) float f32x16;
typedef __attribute__((ext_vector_type(4))) unsigned int u32x4;
typedef __attribute__((ext_vector_type(4))) unsigned short u16x4;

#define MFMA16(a, b, c) __builtin_amdgcn_mfma_f32_16x16x32_bf16(a, b, c, 0, 0, 0)
#define MFMA32(a, b, c) __builtin_amdgcn_mfma_f32_32x32x16_bf16(a, b, c, 0, 0, 0)

#if __has_builtin(__builtin_amdgcn_exp2f)
#define EXP2(x) __builtin_amdgcn_exp2f(x)
#else
#define EXP2(x) exp2f(x)
#endif

__device__ __forceinline__ u16 f2b(float f) {
  u32 u = __builtin_bit_cast(u32, f);
  u = (u + 0x7fffu + ((u >> 16) & 1u)) >> 16;
  return (u16)u;
}

__device__ __forceinline__ u32 pkbf(float lo, float hi) {
  __bf16 a = (__bf16)lo, b = (__bf16)hi;
  return (u32)__builtin_bit_cast(u16, a) | ((u32)__builtin_bit_cast(u16, b) << 16);
}

__device__ __forceinline__ void gload16(const void* g, void* s) {
  __builtin_amdgcn_global_load_lds((const __attribute__((address_space(1))) void*)g,
                                   (__attribute__((address_space(3))) void*)s, 16, 0, 0);
}

// ---------------- cast x (fp32 -> bf16), 8 elems/thread ----------------
__global__ __launch_bounds__(256) void cast_x_k(const float* __restrict__ x,
                                                u16* __restrict__ xb) {
  int i = blockIdx.x * 256 + threadIdx.x;
  const float4* xv = (const float4*)x;
  float4 a = xv[2 * i], b = xv[2 * i + 1];
  u16x8 o;
  o[0] = f2b(a.x); o[1] = f2b(a.y); o[2] = f2b(a.z); o[3] = f2b(a.w);
  o[4] = f2b(b.x); o[5] = f2b(b.y); o[6] = f2b(b.z); o[7] = f2b(b.w);
  ((u16x8*)xb)[i] = o;
}

// ---------------- transpose + cast weights: W[k][n] fp32 -> Wt[n][k] bf16 ----------------
__global__ __launch_bounds__(256) void transpose_w_k(
    const float* __restrict__ W0, const float* __restrict__ W1,
    const float* __restrict__ W2, const float* __restrict__ W3,
    u16* __restrict__ T0, u16* __restrict__ T1, u16* __restrict__ T2, u16* __restrict__ T3) {
  int z = blockIdx.z;
  const float* W = (z == 0) ? W0 : (z == 1) ? W1 : (z == 2) ? W2 : W3;
  u16* T = (z == 0) ? T0 : (z == 1) ? T1 : (z == 2) ? T2 : T3;
  __shared__ float tile[32][33];
  int n0 = blockIdx.x * 32, k0 = blockIdx.y * 32;
  int tx = threadIdx.x, ty = threadIdx.y;  // block (32,8)
#pragma unroll
  for (int r = 0; r < 32; r += 8)
    tile[ty + r][tx] = W[(size_t)(k0 + ty + r) * 1024 + n0 + tx];
  __syncthreads();
#pragma unroll
  for (int r = 0; r < 32; r += 8)
    T[(size_t)(n0 + ty + r) * 1024 + k0 + tx] = f2b(tile[tx][ty + r]);
}

// ---------------- 128x128 bf16 MFMA GEMM, K=N=1024 ----------------
// mode 0: out = head-major bf16 [(b*16+h)][s][hd]
// mode 1: out = fp32 [M][1024]
// mode 2: out = V-transposed bf16 [(b*16+h)][hd][s]
// Grid (bm=64, bn=8): id%8 = bm%8 -> per-XCD working set = 8 A-panels (2MB) +
// 8 B-panels (2MB) = 4MB = L2. Already XCD-optimal; do not swizzle.
__global__ __launch_bounds__(256) void gemm128_k(
    const u16* __restrict__ A, const u16* __restrict__ Bt, const float* __restrict__ bias,
    u16* __restrict__ outb, float* __restrict__ outf, int mode) {
  __shared__ u16 Asm[128 * 32];
  __shared__ u16 Bsm[128 * 32];
  const int K = 1024;
  int bm = blockIdx.x, bn = blockIdx.y;
  int tid = threadIdx.x;
  int lane = tid & 63, wave = tid >> 6;
  int wm = wave >> 1, wn = wave & 1;
  int r = lane & 15, kg = (lane >> 4) * 8;
  f32x4 acc[4][4] = {};
  const u16* Abase = A + (size_t)bm * 128 * K;
  const u16* Bbase = Bt + (size_t)bn * 128 * K;
  for (int k0 = 0; k0 < K; k0 += 32) {
#pragma unroll
    for (int i = 0; i < 2; i++) {
      int c = tid + i * 256;
      int row = c >> 2, ko = (c & 3) * 8;
      gload16(Abase + (size_t)row * K + k0 + ko, Asm + c * 8);
      gload16(Bbase + (size_t)row * K + k0 + ko, Bsm + c * 8);
    }
    __syncthreads();
    bf16x8 af[4], bfr[4];
#pragma unroll
    for (int m = 0; m < 4; m++)
      af[m] = *(const bf16x8*)(Asm + (wm * 64 + m * 16 + r) * 32 + kg);
#pragma unroll
    for (int n = 0; n < 4; n++)
      bfr[n] = *(const bf16x8*)(Bsm + (wn * 64 + n * 16 + r) * 32 + kg);
#pragma unroll
    for (int m = 0; m < 4; m++)
#pragma unroll
      for (int n = 0; n < 4; n++)
        acc[m][n] = MFMA16(af[m], bfr[n], acc[m][n]);
    __syncthreads();
  }
#pragma unroll
  for (int m = 0; m < 4; m++) {
    int grow0 = bm * 128 + wm * 64 + m * 16 + ((lane >> 4) << 2);
#pragma unroll
    for (int n = 0; n < 4; n++) {
      int gcol = bn * 128 + wn * 64 + n * 16 + r;
      float bv = bias[gcol];
#pragma unroll
      for (int e = 0; e < 4; e++) {
        int grow = grow0 + e;
        float v = acc[m][n][e] + bv;
        if (mode == 0) {
          int b = grow >> 11, s = grow & 2047, h = gcol >> 6, hd = gcol & 63;
          outb[(((size_t)(b * 16 + h)) * 2048 + s) * 64 + hd] = f2b(v);
        } else if (mode == 2) {
          int b = grow >> 11, s = grow & 2047, h = gcol >> 6, hd = gcol & 63;
          outb[(((size_t)(b * 16 + h)) * 64 + hd) * 2048 + s] = f2b(v);
        } else {
          outf[(size_t)grow * 1024 + gcol] = v;
        }
      }
    }
  }
}

// ---------------- flash attention: LDS-staged K/V, swapped-operand 32x32 MFMA ----------------
// Q,K: [bh][s][64] bf16. VT: [bh][hd=64][s=2048] bf16. O: [b][s][1024] bf16.
// Block = 256 thr (4 waves), wave owns 32 q-rows. Grid (bh=64, qt=16): id%8=bh%8
// -> per-XCD K/V working set = 4MB = L2 (verified r6).
// K/V tiles (8KB each) staged ONCE per block into double-buffered LDS via
// global_load_lds (4x fewer L2 loads than per-wave reg loads). XOR swizzle
// (16B slot ^= row&7) applied on the GLOBAL SOURCE address (linear LDS dest,
// rule 21) and on ds_read -> 32-way bank conflict reduced to the wave64 floor.
// ONE barrier per tile: stage(kt+1) issued at loop top, drained by the
// end-of-iteration __syncthreads -> full-compute latency cover (T3 minimum).
// Registers: fragments ds_read at use, no prefetch buffers -> ~125 live
// -> 4 waves/SIMD (vs r8's 2).
__global__ __launch_bounds__(256, 4) void attn_k(const u16* __restrict__ Q,
                                                 const u16* __restrict__ Kh,
                                                 const u16* __restrict__ VT,
                                                 u16* __restrict__ O) {
  __shared__ u16 Klds[2][64 * 64];
  __shared__ u16 Vlds[2][64 * 64];
  int bh = blockIdx.x, qt = blockIdx.y;
  int tid = threadIdx.x, lane = tid & 63, w = tid >> 6;
  int c = lane & 31, h = lane >> 5;
  const size_t hoff = (size_t)bh * 2048 * 64;
  const u16* Qb = Q + hoff;
  const u16* Kb = Kh + hoff;
  const u16* Vb = VT + hoff;  // [64][2048]
  const int q = qt * 128 + w * 32 + c;
  const float cs = 0.125f * 1.44269504f;  // softmax scale in log2 domain
  const int sswz = c & 7;                 // read-side slot swizzle for this lane

  // Q as B-fragments: lane(c,h) holds Q[q=c][d = ks*16 + 8h + j]
  bf16x8 qf[4];
#pragma unroll
  for (int ks = 0; ks < 4; ks++)
    qf[ks] = *(const bf16x8*)(Qb + (size_t)q * 64 + ks * 16 + h * 8);

  f32x16 oacc[2] = {};  // O^T frags: oacc[no]: hd = no*32 + (e&3)+8*(e>>2)+4h, col q = c
  float m_run = -1e30f, l_run = 0.f;

  // stage tile kt into buffer buf. Chunk ch = 16B slot index; row = ch>>3 (8 slots/row),
  // phys slot s = ch&7 holds global slot s^(row&7)  (involution; read applies same XOR).
#define STAGE(buf, kt)                                                                   \
  {                                                                                      \
    _Pragma("unroll") for (int i = 0; i < 2; i++) {                                      \
      int ch = tid + i * 256;                                                            \
      int row = ch >> 3, s = ch & 7;                                                     \
      gload16(Kb + (size_t)((kt) * 64 + row) * 64 + (size_t)((s ^ (row & 7)) * 8),       \
              &Klds[buf][ch * 8]);                                                       \
      gload16(Vb + (size_t)row * 2048 + (size_t)((kt) * 64) + (size_t)((s ^ (row & 7)) * 8), \
              &Vlds[buf][ch * 8]);                                                       \
    }                                                                                    \
  }

  int cur = 0;
  STAGE(0, 0);
  __syncthreads();

  for (int kt = 0; kt < 32; kt++) {
    if (kt + 1 < 32) STAGE(cur ^ 1, kt + 1);  // async; drained by end-of-iter barrier
    const u16* Kc = Klds[cur];
    const u16* Vc = Vlds[cur];
    // S^T = K . Q^T : lane(c,h) holds S[q=c][key = n*32+(e&3)+8*(e>>2)+4h]
    f32x16 st[2] = {};
#pragma unroll
    for (int n = 0; n < 2; n++)
#pragma unroll
      for (int ks = 0; ks < 4; ks++) {
        bf16x8 kf = *(const bf16x8*)(Kc + (n * 32 + c) * 64 + ((2 * ks + h) ^ sswz) * 8);
        st[n] = MFMA32(kf, qf[ks], st[n]);
      }
    // ---- softmax (per-lane: one q-row; tree reductions) ----
    float tr[16];
#pragma unroll
    for (int e = 0; e < 16; e++) tr[e] = fmaxf(st[0][e], st[1][e]);
#pragma unroll
    for (int s = 8; s > 0; s >>= 1)
#pragma unroll
      for (int e = 0; e < 8; e++)
        if (e < s) tr[e] = fmaxf(tr[e], tr[e + s]);
    float pmax = fmaxf(tr[0], __shfl_xor(tr[0], 32));
    float ps = pmax * cs;
    // defer-max (T13): rescale only when max grew past THR=8 (log2 domain)
    if (__any(ps > m_run + 8.0f)) {
      float mnew = fmaxf(m_run, ps);
      float corr = EXP2(m_run - mnew);
      m_run = mnew;
      l_run *= corr;
#pragma unroll
      for (int no = 0; no < 2; no++)
#pragma unroll
        for (int e = 0; e < 16; e++) oacc[no][e] *= corr;
    }
    float rs = 0.f;
#pragma unroll
    for (int n = 0; n < 2; n++)
#pragma unroll
      for (int e = 0; e < 16; e++) {
        float p = EXP2(st[n][e] * cs - m_run);
        st[n][e] = p;
        rs += p;
      }
    rs += __shfl_xor(rs, 32);
    l_run += rs;
    // ---- pack P to bf16 B-fragments via half-wave exchange ----
    u32 paw[4][4];
#pragma unroll
    for (int n = 0; n < 2; n++)
#pragma unroll
      for (int t = 0; t < 2; t++) {
        u32 A = pkbf(st[n][8 * t + 0], st[n][8 * t + 1]);
        u32 B = pkbf(st[n][8 * t + 2], st[n][8 * t + 3]);
        u32 C = pkbf(st[n][8 * t + 4], st[n][8 * t + 5]);
        u32 D = pkbf(st[n][8 * t + 6], st[n][8 * t + 7]);
        u32 t0 = __shfl_xor(h ? A : C, 32);
        u32 t1 = __shfl_xor(h ? B : D, 32);
        int sl = n * 2 + t;
        paw[sl][0] = h ? t0 : A;
        paw[sl][1] = h ? t1 : B;
        paw[sl][2] = h ? C : t0;
        paw[sl][3] = h ? D : t1;
      }
    // ---- PV: O^T += V^T . P^T (A-frag from V LDS, B-frag = packed P) ----
#pragma unroll
    for (int no = 0; no < 2; no++)
#pragma unroll
      for (int sl = 0; sl < 4; sl++) {
        bf16x8 vfr = *(const bf16x8*)(Vc + (no * 32 + c) * 64 + ((2 * sl + h) ^ sswz) * 8);
        bf16x8 pf = __builtin_bit_cast(bf16x8, *(u32x4*)paw[sl]);
        oacc[no] = MFMA32(vfr, pf, oacc[no]);
      }
    __syncthreads();  // drains stage(kt+1) vmem + this tile's ds_reads; flips buffers
    cur ^= 1;
  }
  // ---- epilogue: O^T[hd][q] / l -> O[b][s=q][head*64+hd] ----
  int b = bh >> 4, head = bh & 15;
  float inv = 1.0f / l_run;
#pragma unroll
  for (int no = 0; no < 2; no++)
#pragma unroll
    for (int u = 0; u < 4; u++) {
      u16x4 pkt;
#pragma unroll
      for (int v = 0; v < 4; v++) pkt[v] = f2b(oacc[no][4 * u + v] * inv);
      int hd0 = no * 32 + 8 * u + 4 * h;
      *(u16x4*)(O + ((size_t)b * 2048 + q) * 1024 + head * 64 + hd0) = pkt;
    }
#undef STAGE
}

extern "C" void kernel_launch(void* const* d_in, const int* in_sizes, int n_in,
                              void* d_out, int out_size, void* d_ws, size_t ws_size,
                              hipStream_t stream) {
  const float* x = (const float*)d_in[0];
  const float* Wq = (const float*)d_in[1];
  const float* bq = (const float*)d_in[2];
  const float* Wk = (const float*)d_in[3];
  const float* bk = (const float*)d_in[4];
  const float* Wv = (const float*)d_in[5];
  const float* bv = (const float*)d_in[6];
  const float* Wo = (const float*)d_in[7];
  const float* bo = (const float*)d_in[8];
  float* out = (float*)d_out;

  u16* ws = (u16*)d_ws;
  u16* x_bf = ws;                              // 8M u16
  u16* Wt0 = x_bf + 8 * 1024 * 1024;           // 1M each
  u16* Wt1 = Wt0 + 1024 * 1024;
  u16* Wt2 = Wt1 + 1024 * 1024;
  u16* Wt3 = Wt2 + 1024 * 1024;
  u16* Qh = Wt3 + 1024 * 1024;                 // 8M each
  u16* Kh = Qh + 8 * 1024 * 1024;
  u16* Vt = Kh + 8 * 1024 * 1024;              // V transposed [bh][hd][s]
  u16* attn = x_bf;  // alias: x_bf dead after QKV GEMMs

  cast_x_k<<<4096, 256, 0, stream>>>(x, x_bf);
  transpose_w_k<<<dim3(32, 32, 4), dim3(32, 8), 0, stream>>>(Wq, Wk, Wv, Wo, Wt0, Wt1, Wt2, Wt3);
  gemm128_k<<<dim3(64, 8), 256, 0, stream>>>(x_bf, Wt0, bq, Qh, nullptr, 0);
  gemm128_k<<<dim3(64, 8), 256, 0, stream>>>(x_bf, Wt1, bk, Kh, nullptr, 0);
  gemm128_k<<<dim3(64, 8), 256, 0, stream>>>(x_bf, Wt2, bv, Vt, nullptr, 2);
  attn_k<<<dim3(64, 16), 256, 0, stream>>>(Qh, Kh, Vt, attn);
  gemm128_k<<<dim3(64, 8), 256, 0, stream>>>(attn, Wt3, bo, nullptr, out, 1);
}